// Round 4
// baseline (243.524 us; speedup 1.0000x reference)
//
#include <hip/hip_runtime.h>
#include <hip/hip_bf16.h>
#include <math.h>

#define BB 8
#define NN 2048
#define DD 128
#define ALPHA 0.2f
#define LOG2E 1.4426950408889634f

typedef __attribute__((ext_vector_type(8))) short short8;
typedef __attribute__((ext_vector_type(4))) float f32x4;

__device__ inline unsigned short bf16_rne(float v) {
    unsigned int x = __float_as_uint(v);
    unsigned int r = x + 0x7FFFu + ((x >> 16) & 1u);   // round-to-nearest-even
    return (unsigned short)(r >> 16);
}
__device__ inline float bf16_back(unsigned short u) {
    return __uint_as_float(((unsigned int)u) << 16);
}

// ---------------- Kernel 1: f1/f2 scores (pre-scaled by log2e) + bf16 H^T panel ----------------
// Panel layout (per batch): [ks=0..63][n=0..127][c=0..3][e=0..7] bf16,
// element = h[ks*32 + c*8 + e][n]. One wave B-frag load = 1KB contiguous.
__global__ __launch_bounds__(256) void pack_kernel(const float* __restrict__ h,
                                                   const float* __restrict__ a1,
                                                   const float* __restrict__ a2,
                                                   float* __restrict__ f1,
                                                   float* __restrict__ f2,
                                                   unsigned short* __restrict__ panel) {
    __shared__ float hs[32][DD];   // 16 KB
    int blk = blockIdx.x;
    int b   = blk >> 6;            // 64 chunks of 32 rows per batch
    int ks  = blk & 63;
    int r0  = ks * 32;
    int t   = threadIdx.x;

    const float* hb = h + ((size_t)b * NN + r0) * DD;
#pragma unroll
    for (int m = 0; m < 4; ++m) {
        int off = t * 4 + m * 1024;
        *reinterpret_cast<float4*>(&hs[0][0] + off) =
            *reinterpret_cast<const float4*>(hb + off);
    }
    __syncthreads();

    // f-scores: 8 threads per row, 16 d each, shfl-reduce within 8-lane group
    {
        int row = t >> 3, d0 = (t & 7) * 16;
        float s1 = 0.f, s2 = 0.f;
#pragma unroll
        for (int q = 0; q < 4; ++q) {
            float4 hv  = *reinterpret_cast<const float4*>(&hs[row][d0 + q * 4]);
            float4 av1 = *reinterpret_cast<const float4*>(a1 + d0 + q * 4);
            float4 av2 = *reinterpret_cast<const float4*>(a2 + d0 + q * 4);
            s1 += hv.x * av1.x + hv.y * av1.y + hv.z * av1.z + hv.w * av1.w;
            s2 += hv.x * av2.x + hv.y * av2.y + hv.z * av2.z + hv.w * av2.w;
        }
#pragma unroll
        for (int off = 1; off < 8; off <<= 1) {
            s1 += __shfl_xor(s1, off, 64);
            s2 += __shfl_xor(s2, off, 64);
        }
        if ((t & 7) == 0) {
            f1[b * NN + r0 + row] = s1 * LOG2E;   // exp(lrelu(x)) == exp2(lrelu(x*log2e))
            f2[b * NN + r0 + row] = s2 * LOG2E;
        }
    }

    // panel pack: thread -> n = t>>1, c in {(t&1)*2, (t&1)*2+1}
    {
        int n = t >> 1;
        size_t base = (((size_t)b * 64 + ks) * 128 + n) * 32;
#pragma unroll
        for (int cc = 0; cc < 2; ++cc) {
            int c = (t & 1) * 2 + cc;
            short8 v;
#pragma unroll
            for (int e = 0; e < 8; ++e) v[e] = (short)bf16_rne(hs[c * 8 + e][n]);
            *reinterpret_cast<short8*>(panel + base + (size_t)c * 8) = v;
        }
    }
}

// ---------------- Kernel 2: W-gen (regs) + MFMA aggregation ----------------
// Block: 16 rows (1 m-tile), 4 waves each own a K-quarter (512). Prefetched adj stream.
__global__ __launch_bounds__(256, 4) void gat_mfma(const int* __restrict__ adj,
                                                   const float* __restrict__ f1,
                                                   const float* __restrict__ f2,
                                                   const unsigned short* __restrict__ panel,
                                                   float* __restrict__ out) {
    __shared__ float buf[2][16][132];   // 16896 B
    __shared__ float sden[4][16];

    int blk  = blockIdx.x;
    int b    = blk & 7;        // XCD-aligned batch (1024 % 8 == 0, bijective)
    int tile = blk >> 3;       // 128 tiles per batch
    int i0   = tile * 16;
    int t    = threadIdx.x;
    int w    = t >> 6, l = t & 63;
    int lr   = l & 15, lc = l >> 4;    // A/D fragment lane mapping

    const unsigned short* pb = panel + (size_t)b * (64 * 128 * 32);
    const float* f2b = f2 + b * NN;
    const int* arow  = adj + (size_t)b * NN * NN + (size_t)(i0 + lr) * NN;
    float f1r = f1[b * NN + i0 + lr];

    f32x4 acc[8];
#pragma unroll
    for (int nt = 0; nt < 8; ++nt) acc[nt] = (f32x4){0.f, 0.f, 0.f, 0.f};
    float sacc = 0.f;

    int kbase = w * 512;

    // prefetch iteration 0 (adj = the HBM stream; f2 = L2)
    int jb0 = kbase + lc * 8;
    int4   ajN0 = *reinterpret_cast<const int4*>(arow + jb0);
    int4   ajN1 = *reinterpret_cast<const int4*>(arow + jb0 + 4);
    float4 f2N0 = *reinterpret_cast<const float4*>(f2b + jb0);
    float4 f2N1 = *reinterpret_cast<const float4*>(f2b + jb0 + 4);

#pragma unroll
    for (int ks = 0; ks < 16; ++ks) {
        int k0 = kbase + ks * 32;
        int4 a0 = ajN0, a1 = ajN1;
        float4 g0 = f2N0, g1 = f2N1;

        // B fragments for current iter (L2-resident panel; e-loop covers latency)
        const unsigned short* pk = pb + (size_t)(k0 >> 5) * 4096 + lr * 32 + lc * 8;
        short8 bf[8];
#pragma unroll
        for (int nt = 0; nt < 8; ++nt)
            bf[nt] = *reinterpret_cast<const short8*>(pk + nt * 512);

        // prefetch next iter's adj/f2
        if (ks < 15) {
            int jn = k0 + 32 + lc * 8;
            ajN0 = *reinterpret_cast<const int4*>(arow + jn);
            ajN1 = *reinterpret_cast<const int4*>(arow + jn + 4);
            f2N0 = *reinterpret_cast<const float4*>(f2b + jn);
            f2N1 = *reinterpret_cast<const float4*>(f2b + jn + 4);
        }

        float f2v[8] = {g0.x, g0.y, g0.z, g0.w, g1.x, g1.y, g1.z, g1.w};
        int   aj[8]  = {a0.x, a0.y, a0.z, a0.w, a1.x, a1.y, a1.z, a1.w};

        short8 af;
#pragma unroll
        for (int e = 0; e < 8; ++e) {
            float x  = f1r + f2v[e];
            float ee = fmaxf(x, ALPHA * x);                       // lrelu (log2-domain)
            float wv = (aj[e] > 0) ? __builtin_amdgcn_exp2f(ee) : 0.f;
            unsigned short u = bf16_rne(wv);
            sacc += bf16_back(u);                                 // denom from ROUNDED w
            af[e] = (short)u;
        }
#pragma unroll
        for (int nt = 0; nt < 8; ++nt)
            acc[nt] = __builtin_amdgcn_mfma_f32_16x16x32_bf16(af, bf[nt], acc[nt], 0, 0, 0);
    }

    // row denominators: reduce the 4 k-chunk lane groups
    sacc += __shfl_xor(sacc, 16, 64);
    sacc += __shfl_xor(sacc, 32, 64);
    if (l < 16) sden[w][l] = sacc;

    // cross-wave K reduction: pair (0,1)->buf0, (2,3)->buf1
    float* mybuf = &buf[w >> 1][0][0];
    if ((w & 1) == 0) {
#pragma unroll
        for (int nt = 0; nt < 8; ++nt) {
            float* p = mybuf + (lc * 4) * 132 + nt * 16 + lr;
#pragma unroll
            for (int r = 0; r < 4; ++r) p[r * 132] = acc[nt][r];
        }
    }
    __syncthreads();
    if (w & 1) {
#pragma unroll
        for (int nt = 0; nt < 8; ++nt) {
            float* p = mybuf + (lc * 4) * 132 + nt * 16 + lr;
#pragma unroll
            for (int r = 0; r < 4; ++r) p[r * 132] += acc[nt][r];
        }
    }
    __syncthreads();

    // epilogue: thread t -> row t>>4, cols (t&15)*8 .. +8 ; out = elu((buf0+buf1)/den)
    {
        int row = t >> 4, col0 = (t & 15) * 8;
        float den = sden[0][row] + sden[1][row] + sden[2][row] + sden[3][row];
        float inv = 1.0f / den;
        float* ob = out + ((size_t)b * NN + i0 + row) * DD;
#pragma unroll
        for (int q = 0; q < 2; ++q) {
            int col = col0 + q * 4;
            float4 v0 = *reinterpret_cast<const float4*>(&buf[0][row][col]);
            float4 v1 = *reinterpret_cast<const float4*>(&buf[1][row][col]);
            float r0 = (v0.x + v1.x) * inv;
            float r1 = (v0.y + v1.y) * inv;
            float r2 = (v0.z + v1.z) * inv;
            float r3 = (v0.w + v1.w) * inv;
            r0 = (r0 > 0.f) ? r0 : expm1f(r0);
            r1 = (r1 > 0.f) ? r1 : expm1f(r1);
            r2 = (r2 > 0.f) ? r2 : expm1f(r2);
            r3 = (r3 > 0.f) ? r3 : expm1f(r3);
            *reinterpret_cast<float4*>(ob + col) = make_float4(r0, r1, r2, r3);
        }
    }
}

extern "C" void kernel_launch(void* const* d_in, const int* in_sizes, int n_in,
                              void* d_out, int out_size, void* d_ws, size_t ws_size,
                              hipStream_t stream) {
    const float* h   = (const float*)d_in[0];
    const int*   adj = (const int*)d_in[1];
    const float* a1  = (const float*)d_in[2];
    const float* a2  = (const float*)d_in[3];
    float* out = (float*)d_out;

    float* f1 = (float*)d_ws;                                   // 16384 floats
    float* f2 = f1 + BB * NN;                                   // 16384 floats
    unsigned short* panel = (unsigned short*)(f2 + BB * NN);    // 2M bf16 = 4MB

    pack_kernel<<<BB * 64, 256, 0, stream>>>(h, a1, a2, f1, f2, panel);
    gat_mfma<<<BB * 128, 256, 0, stream>>>(adj, f1, f2, panel, out);
}